// Round 6
// baseline (939.772 us; speedup 1.0000x reference)
//
#include <hip/hip_runtime.h>
#include <hip/hip_bf16.h>

typedef __bf16 bf16x8 __attribute__((ext_vector_type(8)));
typedef __bf16 bf16x2 __attribute__((ext_vector_type(2)));
typedef float  f32x4  __attribute__((ext_vector_type(4)));
typedef float  f32x2  __attribute__((ext_vector_type(2)));

#define N_IN 1024
#define BM   32
#define NTHR 512

// Convert B (fp32, 1024x1024) to bf16 in workspace.
__global__ void convB_kernel(const float* __restrict__ B, __bf16* __restrict__ Bb) {
    int i = blockIdx.x * blockDim.x + threadIdx.x;
    f32x4 v = ((const f32x4*)B)[i];
    __bf16 o0 = (__bf16)v[0], o1 = (__bf16)v[1], o2 = (__bf16)v[2], o3 = (__bf16)v[3];
    bf16x2 p0; p0[0] = o0; p0[1] = o1;
    bf16x2 p1; p1[0] = o2; p1[1] = o3;
    ((bf16x2*)Bb)[2 * i]     = p0;
    ((bf16x2*)Bb)[2 * i + 1] = p1;
}

// Fused: o = num * avg^alpha (staged to 64KB LDS panel -> 2 blocks/CU),
// Y = O @ B^T via MFMA, out[b] = sum_i o_i*(A_i + Y_i) + C.
// BM=32: two independent blocks per CU interleave -> block-level latency hiding.
template<bool USEBF>
__global__ __launch_bounds__(NTHR, 4)   // 4 waves/EU = 2 blocks/CU
void fused_kernel(const float* __restrict__ x, const float* __restrict__ A,
                  const float* __restrict__ Bf, const __bf16* __restrict__ Bb,
                  const float* __restrict__ Cp, const float* __restrict__ alpha,
                  float* __restrict__ out) {
    __shared__ __align__(16) __bf16 o_panel[BM * N_IN];   // 64 KB, XOR-swizzled
    __shared__ float rowsum[8][BM];                       // 1 KB

    const int t    = threadIdx.x;
    const int wave = t >> 6;
    const int lane = t & 63;
    const int lrow = lane & 15;   // frag row / col within 16
    const int lgrp = lane >> 4;   // k-group (0..3)
    const long blk_row = (long)blockIdx.x * BM;

    // staging role: 16 threads per row, 2 consecutive k each, 32-k chunks
    const int srow  = t >> 4;        // 0..31
    const int skoff = (t & 15) * 2;  // 0,2,...,30
    const float* xrow = x + (blk_row + srow) * (2 * N_IN);
    const int ssw   = (srow & 7) << 3;
    const int sbase = srow * N_IN;

    // ---- prologue: stage chunks 0..7 (k 0..255) ----
    #pragma unroll
    for (int c = 0; c < 8; ++c) {
        int k = c * 32 + skoff;
        f32x2 sa  = *(const f32x2*)(xrow + k);
        f32x2 sn  = *(const f32x2*)(xrow + N_IN + k);
        f32x2 sal = *(const f32x2*)(alpha + k);
        bf16x2 w2;
        w2[0] = (__bf16)(sn[0] * __expf(sal[0] * __logf(sa[0])));
        w2[1] = (__bf16)(sn[1] * __expf(sal[1] * __logf(sa[1])));
        *(bf16x2*)&o_panel[sbase + ((k & ~7) ^ ssw) + (k & 7)] = w2;
    }
    __syncthreads();

    f32x4 acc[2][8];
    #pragma unroll
    for (int m = 0; m < 2; ++m)
        #pragma unroll
        for (int n = 0; n < 8; ++n)
            acc[m][n] = f32x4{0.f, 0.f, 0.f, 0.f};

    // ---- main loop: 4 quarters x 8 kc; stage chunk kc+8 during iter kc ----
    #pragma unroll 1
    for (int q = 0; q < 4; ++q) {
        #pragma unroll
        for (int kq = 0; kq < 8; ++kq) {
            const int kc = q * 8 + kq;
            const bool staging = (q < 3);
            const int kk = kc * 32 + lgrp * 8;

            // x-staging loads first (r2-proven order)
            f32x2 sa, sn, sal;
            if (staging) {
                int k = (kc + 8) * 32 + skoff;
                sa  = *(const f32x2*)(xrow + k);
                sn  = *(const f32x2*)(xrow + N_IN + k);
                sal = *(const f32x2*)(alpha + k);
            }

            // A-frags from swizzled LDS
            bf16x8 afr[2];
            #pragma unroll
            for (int m = 0; m < 2; ++m) {
                int r = m * 16 + lrow;
                afr[m] = *(const bf16x8*)&o_panel[r * N_IN + (kk ^ ((r & 7) << 3))];
            }

            // B-frags direct from L2 (same 2MB B for all blocks -> L2-hot)
            bf16x8 bfr[8];
            #pragma unroll
            for (int n = 0; n < 8; ++n) {
                int i = wave * 128 + n * 16 + lrow;
                if constexpr (USEBF) {
                    bfr[n] = *(const bf16x8*)&Bb[(long)i * N_IN + kk];
                } else {
                    const float* p = Bf + (long)i * N_IN + kk;
                    f32x4 lo = *(const f32x4*)p;
                    f32x4 hi = *(const f32x4*)(p + 4);
                    #pragma unroll
                    for (int e = 0; e < 4; ++e) {
                        bfr[n][e]     = (__bf16)lo[e];
                        bfr[n][e + 4] = (__bf16)hi[e];
                    }
                }
            }

            #pragma unroll
            for (int m = 0; m < 2; ++m)
                #pragma unroll
                for (int n = 0; n < 8; ++n)
                    acc[m][n] = __builtin_amdgcn_mfma_f32_16x16x32_bf16(
                        afr[m], bfr[n], acc[m][n], 0, 0, 0);

            // pow + swizzled LDS write of chunk kc+8
            if (staging) {
                int k = (kc + 8) * 32 + skoff;
                bf16x2 w2;
                w2[0] = (__bf16)(sn[0] * __expf(sal[0] * __logf(sa[0])));
                w2[1] = (__bf16)(sn[1] * __expf(sal[1] * __logf(sa[1])));
                *(bf16x2*)&o_panel[sbase + ((k & ~7) ^ ssw) + (k & 7)] = w2;
            }
        }
        __syncthreads();   // quarter boundary: staged chunks visible
    }

    // ---- epilogue: rowpart[r] += (Y[r][i] + A[i]) * o[r][i] ----
    float rp[8];
    #pragma unroll
    for (int i = 0; i < 8; ++i) rp[i] = 0.f;
    #pragma unroll
    for (int n = 0; n < 8; ++n) {
        int i = wave * 128 + n * 16 + lrow;
        float Ai = A[i];
        #pragma unroll
        for (int m = 0; m < 2; ++m)
            #pragma unroll
            for (int j = 0; j < 4; ++j) {
                int r = m * 16 + lgrp * 4 + j;    // C/D layout (m89-verified)
                float y  = acc[m][n][j] + Ai;
                float ov = (float)o_panel[r * N_IN + ((i & ~7) ^ ((r & 7) << 3)) + (i & 7)];
                rp[m * 4 + j] += y * ov;
            }
    }

    // reduce over the 16 lanes sharing the same rows
    #pragma unroll
    for (int d = 1; d < 16; d <<= 1) {
        #pragma unroll
        for (int i = 0; i < 8; ++i)
            rp[i] += __shfl_xor(rp[i], d);
    }
    if (lrow == 0) {
        #pragma unroll
        for (int m = 0; m < 2; ++m)
            #pragma unroll
            for (int j = 0; j < 4; ++j)
                rowsum[wave][m * 16 + lgrp * 4 + j] = rp[m * 4 + j];
    }
    __syncthreads();
    if (t < BM) {
        float s = Cp[0];
        #pragma unroll
        for (int w = 0; w < 8; ++w) s += rowsum[w][t];
        out[blk_row + t] = s;
    }
}

extern "C" void kernel_launch(void* const* d_in, const int* in_sizes, int n_in,
                              void* d_out, int out_size, void* d_ws, size_t ws_size,
                              hipStream_t stream) {
    const float* x     = (const float*)d_in[0];
    const float* A     = (const float*)d_in[1];
    const float* B     = (const float*)d_in[2];
    const float* C     = (const float*)d_in[3];
    const float* alpha = (const float*)d_in[4];
    float* out = (float*)d_out;

    int batch = in_sizes[0] / (2 * N_IN);   // 65536
    int grid  = batch / BM;                 // 2048

    bool useBf = (ws_size >= (size_t)(N_IN * N_IN * sizeof(__bf16)));
    if (useBf) {
        __bf16* Bb = (__bf16*)d_ws;
        int nvec = (N_IN * N_IN) / 4;
        convB_kernel<<<nvec / 256, 256, 0, stream>>>(B, Bb);
        fused_kernel<true><<<grid, NTHR, 0, stream>>>(x, A, nullptr, Bb, C, alpha, out);
    } else {
        fused_kernel<false><<<grid, NTHR, 0, stream>>>(x, A, B, nullptr, C, alpha, out);
    }
}

// Round 7
// 391.139 us; speedup vs baseline: 2.4027x; 2.4027x over previous
//
#include <hip/hip_runtime.h>
#include <hip/hip_bf16.h>

typedef __bf16 bf16x8 __attribute__((ext_vector_type(8)));
typedef __bf16 bf16x4 __attribute__((ext_vector_type(4)));
typedef __bf16 bf16x2 __attribute__((ext_vector_type(2)));
typedef float  f32x4  __attribute__((ext_vector_type(4)));
typedef float  f32x2  __attribute__((ext_vector_type(2)));

#define N_IN 1024
#define BM   64
#define NTHR 512

// ---------- kernel 0: B (fp32) -> bf16 ----------
__global__ void convB_kernel(const float* __restrict__ B, __bf16* __restrict__ Bb) {
    int i = blockIdx.x * blockDim.x + threadIdx.x;
    f32x4 v = ((const f32x4*)B)[i];
    bf16x4 o;
    o[0] = (__bf16)v[0]; o[1] = (__bf16)v[1]; o[2] = (__bf16)v[2]; o[3] = (__bf16)v[3];
    ((bf16x4*)Bb)[i] = o;
}

// ---------- kernel 1: O = num * avg^alpha (pure streaming) ----------
__global__ __launch_bounds__(256)
void pow_kernel(const float* __restrict__ x, const float* __restrict__ alpha,
                __bf16* __restrict__ O, int nvec) {
    for (int v = blockIdx.x * blockDim.x + threadIdx.x; v < nvec;
         v += gridDim.x * blockDim.x) {
        int row = v >> 7;            // 128 bf16x8 chunks per row
        int k   = (v & 127) << 3;
        const float* xr = x + (long)row * (2 * N_IN);
        f32x4 a0 = *(const f32x4*)(xr + k);
        f32x4 a1 = *(const f32x4*)(xr + k + 4);
        f32x4 n0 = *(const f32x4*)(xr + N_IN + k);
        f32x4 n1 = *(const f32x4*)(xr + N_IN + k + 4);
        f32x4 l0 = *(const f32x4*)(alpha + k);
        f32x4 l1 = *(const f32x4*)(alpha + k + 4);
        bf16x8 w;
        #pragma unroll
        for (int e = 0; e < 4; ++e) {
            w[e]     = (__bf16)(n0[e] * __expf(l0[e] * __logf(a0[e])));
            w[e + 4] = (__bf16)(n1[e] * __expf(l1[e] * __logf(a1[e])));
        }
        *(bf16x8*)(O + (long)row * N_IN + k) = w;
    }
}

// ---------- kernel 2: out[b] = sum_i o_i*(A_i + (O B^T)_i) + C ----------
// o_panel staged ONCE from O (no pow), then a barrier-free K-loop:
// only L2-hot B loads in the vmcnt queue, double-buffered at distance 2.
__global__ __launch_bounds__(NTHR, 2)
void qf_kernel(const __bf16* __restrict__ O, const __bf16* __restrict__ Bb,
               const float* __restrict__ A, const float* __restrict__ Cp,
               float* __restrict__ out) {
    __shared__ __align__(16) __bf16 o_panel[BM * N_IN];   // 128 KB, XOR-swizzled
    __shared__ float rowsum[8][BM];

    const int t    = threadIdx.x;
    const int wave = t >> 6;
    const int lane = t & 63;
    const int lrow = lane & 15;
    const int lgrp = lane >> 4;
    const long blk_row = (long)blockIdx.x * BM;
    const __bf16* Orow = O + blk_row * N_IN;

    // ---- prologue: stage o_panel (swizzled) from O ----
    {
        const int srow  = t >> 3;          // 0..63
        const int sk    = (t & 7) * 8;     // 8-aligned
        const int sw    = (srow & 7) << 3;
        #pragma unroll
        for (int c = 0; c < 16; ++c) {
            int k = c * 64 + sk;
            bf16x8 v = *(const bf16x8*)(Orow + (long)srow * N_IN + k);
            *(bf16x8*)&o_panel[srow * N_IN + (k ^ sw)] = v;
        }
    }
    __syncthreads();

    f32x4 acc[4][8];
    #pragma unroll
    for (int m = 0; m < 4; ++m)
        #pragma unroll
        for (int n = 0; n < 8; ++n)
            acc[m][n] = f32x4{0.f, 0.f, 0.f, 0.f};

    const __bf16* bbase = Bb + (long)(wave * 128 + lrow) * N_IN + lgrp * 8;
    auto loadB = [&](bf16x8* dst, int kc) {
        #pragma unroll
        for (int n = 0; n < 8; ++n)
            dst[n] = *(const bf16x8*)(bbase + (long)n * 16 * N_IN + kc * 32);
    };

    bf16x8 b0[8], b1[8];
    loadB(b0, 0);
    loadB(b1, 1);

    // ---- main loop: no barriers, counted vmcnt via distance-2 prefetch ----
    #pragma unroll 2
    for (int kc = 0; kc < 32; ++kc) {
        bf16x8* cur = (kc & 1) ? b1 : b0;
        const int kk = kc * 32 + lgrp * 8;
        bf16x8 afr[4];
        #pragma unroll
        for (int m = 0; m < 4; ++m) {
            int r = m * 16 + lrow;
            afr[m] = *(const bf16x8*)&o_panel[r * N_IN + (kk ^ ((r & 7) << 3))];
        }
        #pragma unroll
        for (int m = 0; m < 4; ++m)
            #pragma unroll
            for (int n = 0; n < 8; ++n)
                acc[m][n] = __builtin_amdgcn_mfma_f32_16x16x32_bf16(
                    afr[m], cur[n], acc[m][n], 0, 0, 0);
        if (kc + 2 < 32) loadB(cur, kc + 2);
    }

    // ---- epilogue: rowpart[r] = sum_i (Y[r][i] + A[i]) * o[r][i] ----
    float rp[16];
    #pragma unroll
    for (int i = 0; i < 16; ++i) rp[i] = 0.f;
    #pragma unroll
    for (int n = 0; n < 8; ++n) {
        const int i = wave * 128 + n * 16 + lrow;
        const float Ai = A[i];
        #pragma unroll
        for (int m = 0; m < 4; ++m)
            #pragma unroll
            for (int j = 0; j < 4; ++j) {
                const int r = m * 16 + lgrp * 4 + j;   // C/D layout (m89-verified)
                float ov = (float)o_panel[r * N_IN + ((i & ~7) ^ ((r & 7) << 3)) + (i & 7)];
                rp[m * 4 + j] += (acc[m][n][j] + Ai) * ov;
            }
    }
    #pragma unroll
    for (int d = 1; d < 16; d <<= 1)
        #pragma unroll
        for (int i = 0; i < 16; ++i)
            rp[i] += __shfl_xor(rp[i], d);
    if (lrow == 0) {
        #pragma unroll
        for (int m = 0; m < 4; ++m)
            #pragma unroll
            for (int j = 0; j < 4; ++j)
                rowsum[wave][m * 16 + lgrp * 4 + j] = rp[m * 4 + j];
    }
    __syncthreads();
    if (t < BM) {
        float s = Cp[0];
        #pragma unroll
        for (int w = 0; w < 8; ++w) s += rowsum[w][t];
        out[blk_row + t] = s;
    }
}

// ---------- fallback: round-2 fused kernel (used if ws too small) ----------
template<bool USEBF>
__global__ __launch_bounds__(NTHR, 2)
void fused_kernel(const float* __restrict__ x, const float* __restrict__ A,
                  const float* __restrict__ Bf, const __bf16* __restrict__ Bb,
                  const float* __restrict__ Cp, const float* __restrict__ alpha,
                  float* __restrict__ out) {
    __shared__ __align__(16) __bf16 o_panel[BM * N_IN];
    __shared__ float rowsum[8][BM];
    const int t = threadIdx.x, wave = t >> 6, lane = t & 63;
    const int lrow = lane & 15, lgrp = lane >> 4;
    const long blk_row = (long)blockIdx.x * BM;
    const int srow = t >> 3, skoff = (t & 7) * 4;
    const float* xrow = x + (blk_row + srow) * (2 * N_IN);
    #pragma unroll
    for (int c = 0; c < 8; ++c) {
        int k = c * 32 + skoff;
        f32x4 sa = *(const f32x4*)(xrow + k);
        f32x4 sn = *(const f32x4*)(xrow + N_IN + k);
        f32x4 sal = *(const f32x4*)(alpha + k);
        bf16x4 w4;
        #pragma unroll
        for (int e = 0; e < 4; ++e)
            w4[e] = (__bf16)(sn[e] * __expf(sal[e] * __logf(sa[e])));
        *(bf16x4*)&o_panel[srow * N_IN + ((k & ~7) ^ ((srow & 7) << 3)) + (k & 7)] = w4;
    }
    __syncthreads();
    f32x4 acc[2][4][4];
    #pragma unroll
    for (int h = 0; h < 2; ++h)
        #pragma unroll
        for (int m = 0; m < 4; ++m)
            #pragma unroll
            for (int n = 0; n < 4; ++n)
                acc[h][m][n] = f32x4{0.f, 0.f, 0.f, 0.f};
    #pragma unroll 1
    for (int q = 0; q < 4; ++q) {
        #pragma unroll
        for (int kq = 0; kq < 8; ++kq) {
            const int kc = q * 8 + kq;
            const bool staging = (q < 3);
            const int kk = kc * 32 + lgrp * 8;
            f32x4 sa, sn, sal;
            if (staging) {
                int k = (kc + 8) * 32 + skoff;
                sa = *(const f32x4*)(xrow + k);
                sn = *(const f32x4*)(xrow + N_IN + k);
                sal = *(const f32x4*)(alpha + k);
            }
            bf16x8 afr[4];
            #pragma unroll
            for (int m = 0; m < 4; ++m) {
                int r = m * 16 + lrow;
                afr[m] = *(const bf16x8*)&o_panel[r * N_IN + (kk ^ ((r & 7) << 3))];
            }
            bf16x8 bfr[2][4];
            #pragma unroll
            for (int h = 0; h < 2; ++h)
                #pragma unroll
                for (int n = 0; n < 4; ++n) {
                    int i = h * 512 + wave * 64 + n * 16 + lrow;
                    if constexpr (USEBF) {
                        bfr[h][n] = *(const bf16x8*)&Bb[(long)i * N_IN + kk];
                    } else {
                        const float* p = Bf + (long)i * N_IN + kk;
                        f32x4 lo = *(const f32x4*)p;
                        f32x4 hi = *(const f32x4*)(p + 4);
                        #pragma unroll
                        for (int e = 0; e < 4; ++e) {
                            bfr[h][n][e] = (__bf16)lo[e];
                            bfr[h][n][e + 4] = (__bf16)hi[e];
                        }
                    }
                }
            #pragma unroll
            for (int h = 0; h < 2; ++h)
                #pragma unroll
                for (int m = 0; m < 4; ++m)
                    #pragma unroll
                    for (int n = 0; n < 4; ++n)
                        acc[h][m][n] = __builtin_amdgcn_mfma_f32_16x16x32_bf16(
                            afr[m], bfr[h][n], acc[h][m][n], 0, 0, 0);
            if (staging) {
                int k = (kc + 8) * 32 + skoff;
                bf16x4 w4;
                #pragma unroll
                for (int e = 0; e < 4; ++e)
                    w4[e] = (__bf16)(sn[e] * __expf(sal[e] * __logf(sa[e])));
                *(bf16x4*)&o_panel[srow * N_IN + ((k & ~7) ^ ((srow & 7) << 3)) + (k & 7)] = w4;
            }
        }
        __syncthreads();
    }
    float rowpart[16];
    #pragma unroll
    for (int i = 0; i < 16; ++i) rowpart[i] = 0.f;
    #pragma unroll
    for (int h = 0; h < 2; ++h)
        #pragma unroll
        for (int n = 0; n < 4; ++n) {
            int i = h * 512 + wave * 64 + n * 16 + lrow;
            float Ai = A[i];
            #pragma unroll
            for (int m = 0; m < 4; ++m)
                #pragma unroll
                for (int j = 0; j < 4; ++j) {
                    int r = m * 16 + lgrp * 4 + j;
                    float y = acc[h][m][n][j] + Ai;
                    float ov = (float)o_panel[r * N_IN + ((i & ~7) ^ ((r & 7) << 3)) + (i & 7)];
                    rowpart[m * 4 + j] += y * ov;
                }
        }
    #pragma unroll
    for (int d = 1; d < 16; d <<= 1)
        #pragma unroll
        for (int i = 0; i < 16; ++i)
            rowpart[i] += __shfl_xor(rowpart[i], d);
    if (lrow == 0) {
        #pragma unroll
        for (int m = 0; m < 4; ++m)
            #pragma unroll
            for (int j = 0; j < 4; ++j)
                rowsum[wave][m * 16 + lgrp * 4 + j] = rowpart[m * 4 + j];
    }
    __syncthreads();
    if (t < BM) {
        float s = Cp[0];
        #pragma unroll
        for (int w = 0; w < 8; ++w) s += rowsum[w][t];
        out[blk_row + t] = s;
    }
}

extern "C" void kernel_launch(void* const* d_in, const int* in_sizes, int n_in,
                              void* d_out, int out_size, void* d_ws, size_t ws_size,
                              hipStream_t stream) {
    const float* x     = (const float*)d_in[0];
    const float* A     = (const float*)d_in[1];
    const float* B     = (const float*)d_in[2];
    const float* C     = (const float*)d_in[3];
    const float* alpha = (const float*)d_in[4];
    float* out = (float*)d_out;

    const int batch = in_sizes[0] / (2 * N_IN);       // 65536
    const size_t bb_bytes = (size_t)N_IN * N_IN * 2;  // 2 MB
    const size_t o_bytes  = (size_t)batch * N_IN * 2; // 128 MB

    if (ws_size >= bb_bytes + o_bytes) {
        __bf16* Bb = (__bf16*)d_ws;
        __bf16* O  = (__bf16*)((char*)d_ws + bb_bytes);
        convB_kernel<<<(N_IN * N_IN / 4) / 256, 256, 0, stream>>>(B, Bb);
        int nvec = batch * (N_IN / 8);
        pow_kernel<<<2048, 256, 0, stream>>>(x, alpha, O, nvec);
        qf_kernel<<<batch / BM, NTHR, 0, stream>>>(O, Bb, A, C, out);
    } else if (ws_size >= bb_bytes) {
        __bf16* Bb = (__bf16*)d_ws;
        convB_kernel<<<(N_IN * N_IN / 4) / 256, 256, 0, stream>>>(B, Bb);
        fused_kernel<true><<<batch / BM, NTHR, 0, stream>>>(x, A, nullptr, Bb, C, alpha, out);
    } else {
        fused_kernel<false><<<batch / BM, NTHR, 0, stream>>>(x, A, B, nullptr, C, alpha, out);
    }
}